// Round 6
// baseline (1125.243 us; speedup 1.0000x reference)
//
#include <hip/hip_runtime.h>

constexpr int FIN   = 128;   // input features
constexpr int HH    = 64;    // half hidden (GCN branch width)
constexpr int BSH   = 7;     // log2(nodes per bucket)
constexpr int BNODE = 1 << BSH;   // 128 nodes / bucket

// ---- bf16 helpers (manual, RNE) ----
__device__ __forceinline__ unsigned short f2bf(float f) {
    unsigned u = __float_as_uint(f);
    u += 0x7FFFu + ((u >> 16) & 1u);
    return (unsigned short)(u >> 16);
}
__device__ __forceinline__ float bf2f(unsigned short u) {
    return __uint_as_float((unsigned)u << 16);
}

// ------------------------------------------------------------------ GEMM ----
// [xwg | xwf] = x[N,128] @ [W1 | Wf1];  xwg = bf16 GCN half, xwf = fp32 half
__global__ __launch_bounds__(256) void k_gemm(
    const float* __restrict__ x, const float* __restrict__ W1,
    const float* __restrict__ Wf1, unsigned short* __restrict__ xwg,
    float* __restrict__ xwf, int N)
{
    __shared__ float xs[16][68];
    __shared__ float ws[16][128];

    const int tid = threadIdx.x;
    const int tx  = tid & 31;
    const int ty  = tid >> 5;
    const int nbase = blockIdx.x * 64;

    float acc[8][4];
#pragma unroll
    for (int i = 0; i < 8; ++i)
#pragma unroll
        for (int j = 0; j < 4; ++j) acc[i][j] = 0.0f;

    const int xr_row = tid >> 2;
    const int xr_kk0 = (tid & 3) * 4;
    int nload = nbase + xr_row;
    const int nclamped = (nload < N) ? nload : (N - 1);

    const int wk = tid >> 4;
    const int wc = (tid * 8) & 127;

    for (int k0 = 0; k0 < FIN; k0 += 16) {
        float4 xv = *(const float4*)(x + (size_t)nclamped * FIN + k0 + xr_kk0);
        xs[xr_kk0 + 0][xr_row] = xv.x;
        xs[xr_kk0 + 1][xr_row] = xv.y;
        xs[xr_kk0 + 2][xr_row] = xv.z;
        xs[xr_kk0 + 3][xr_row] = xv.w;
        {
            const float* src = (wc < HH) ? (W1  + (size_t)(k0 + wk) * HH + wc)
                                         : (Wf1 + (size_t)(k0 + wk) * HH + (wc - HH));
            float4 w0 = *(const float4*)(src);
            float4 w1 = *(const float4*)(src + 4);
            *(float4*)&ws[wk][wc]     = w0;
            *(float4*)&ws[wk][wc + 4] = w1;
        }
        __syncthreads();

#pragma unroll
        for (int kk = 0; kk < 16; ++kk) {
            float4 xa = *(const float4*)&xs[kk][ty * 8];
            float4 xb = *(const float4*)&xs[kk][ty * 8 + 4];
            float4 wv = *(const float4*)&ws[kk][tx * 4];
            float xr[8] = {xa.x, xa.y, xa.z, xa.w, xb.x, xb.y, xb.z, xb.w};
#pragma unroll
            for (int i = 0; i < 8; ++i) {
                acc[i][0] = fmaf(xr[i], wv.x, acc[i][0]);
                acc[i][1] = fmaf(xr[i], wv.y, acc[i][1]);
                acc[i][2] = fmaf(xr[i], wv.z, acc[i][2]);
                acc[i][3] = fmaf(xr[i], wv.w, acc[i][3]);
            }
        }
        __syncthreads();
    }

#pragma unroll
    for (int i = 0; i < 8; ++i) {
        int n = nbase + ty * 8 + i;
        if (n < N) {
            if (tx < 16) {
                ushort4 v;
                v.x = f2bf(acc[i][0]); v.y = f2bf(acc[i][1]);
                v.z = f2bf(acc[i][2]); v.w = f2bf(acc[i][3]);
                *(ushort4*)(xwg + (size_t)n * HH + tx * 4) = v;
            } else {
                float4 v = make_float4(acc[i][0], acc[i][1], acc[i][2], acc[i][3]);
                *(float4*)(xwf + (size_t)n * HH + (tx - 16) * 4) = v;
            }
        }
    }
}

// ----------------------------------------------------------- bucket build ---
// count per-node degree (for dinv) and per-(bucket,stripe) record counts.
// stripe = blockIdx&7 must match k_scatter's mapping (same grid shape).
__global__ void k_count(const int* __restrict__ col, int* __restrict__ cnt,
                        int* __restrict__ cur, int E)
{
    int e = blockIdx.x * blockDim.x + threadIdx.x;
    if (e >= E) return;
    int c = col[e];
    atomicAdd(cnt + c, 1);
    atomicAdd(cur + ((c >> BSH) * 8 + (blockIdx.x & 7)), 1);
}

// single-block scan: cur[] counts -> exclusive offsets (in place);
// bstart[b] = bucket start, bstart[NB] = E
__global__ __launch_bounds__(1024) void k_scanB(
    int* __restrict__ cur, int* __restrict__ bstart, int NB, int E)
{
    __shared__ int s[1024];
    const int t = threadIdx.x;
    const int total = NB * 8;
    const int CH = 7;                 // 1024*7 = 7168 >= 6256
    int v[CH]; int mysum = 0;
#pragma unroll
    for (int q = 0; q < CH; ++q) {
        int idx = t * CH + q;
        v[q] = (idx < total) ? cur[idx] : 0;
        mysum += v[q];
    }
    s[t] = mysum;
    __syncthreads();
    for (int o = 1; o < 1024; o <<= 1) {
        int y = (t >= o) ? s[t - o] : 0;
        __syncthreads();
        s[t] += y;
        __syncthreads();
    }
    int running = s[t] - mysum;
#pragma unroll
    for (int q = 0; q < CH; ++q) {
        int idx = t * CH + q;
        if (idx < total) cur[idx] = running;
        running += v[q];
    }
    __syncthreads();
    for (int b = t; b < NB; b += 1024) bstart[b] = cur[b * 8];
    if (t == 0) bstart[NB] = E;
}

__global__ void k_dinv(const int* __restrict__ cnt, float* __restrict__ dinv, int N) {
    int i = blockIdx.x * blockDim.x + threadIdx.x;
    if (i < N) dinv[i] = rsqrtf((float)cnt[i] + 1.0f);
}

// recs[pos] = { row | (c_local<<17), norm }, appended per (bucket,stripe).
// Sequential positions per cursor -> full-line write combining in the XCD L2.
__global__ void k_scatter(const int* __restrict__ ei, const float* __restrict__ dinv,
                          int* __restrict__ cur, int2* __restrict__ recs, int E)
{
    int e = blockIdx.x * blockDim.x + threadIdx.x;
    if (e >= E) return;
    int r = ei[e], c = ei[E + e];
    float nrm = dinv[r] * dinv[c];
    int pos = atomicAdd(cur + ((c >> BSH) * 8 + (blockIdx.x & 7)), 1);
    recs[pos] = make_int2(r | ((c & (BNODE - 1)) << 17), __float_as_int(nrm));
}

// --------------- layer-1: bucket-LDS aggregate + relu + layer-2 dots --------
// one block per bucket of 128 nodes; acc[128][64] f32 in LDS (32 KB).
// 16 waves stream the bucket's records; lane = feature.
__global__ __launch_bounds__(1024) void k_bagg(
    const int* __restrict__ bstart, const int2* __restrict__ recs,
    const float* __restrict__ dinv,
    const unsigned short* __restrict__ xwg, const float* __restrict__ xwf,
    const float* __restrict__ b1, const float* __restrict__ bf1,
    const float* __restrict__ W2, const float* __restrict__ Wf2,
    const float* __restrict__ b2, const float* __restrict__ bf2,
    float* __restrict__ z, float* __restrict__ out, int N)
{
    __shared__ float acc[BNODE * 64];
    const int bkt  = blockIdx.x;
    const int tid  = threadIdx.x;
    const int wave = tid >> 6;
    const int lane = tid & 63;

    for (int t = tid; t < BNODE * 64; t += 1024) acc[t] = 0.0f;
    __syncthreads();

    const int jb = bstart[bkt], je = bstart[bkt + 1];
    for (int j0 = jb + wave * 64; j0 < je; j0 += 16 * 64) {
        int2 r = (j0 + lane < je) ? recs[j0 + lane] : make_int2(0, 0);
        const int lim = min(64, je - j0);
#pragma unroll 4
        for (int t = 0; t < lim; ++t) {
            int   pk = __shfl(r.x, t, 64);
            float nr = __shfl(__int_as_float(r.y), t, 64);
            int row = pk & 0x1FFFF;
            int cl  = pk >> 17;
            float v = bf2f(xwg[(size_t)row * HH + lane]) * nr;
            atomicAdd(&acc[cl * 64 + lane], v);
        }
    }
    __syncthreads();

    // epilogue: 8 nodes per wave
    const float b1v  = b1[lane],  bf1v = bf1[lane];
    const float w2a  = W2[lane],  w2b  = W2[HH + lane];
    const float wf2a = Wf2[lane], wf2b = Wf2[HH + lane];
    const float obias = b2[0] + bf2[0];

    for (int n = wave; n < BNODE; n += 16) {
        int i = bkt * BNODE + n;
        if (i >= N) continue;
        float di = dinv[i];
        float self = bf2f(xwg[(size_t)i * HH + lane]) * di * di;
        float h0 = fmaxf(acc[n * 64 + lane] + self + b1v, 0.0f);
        float h1 = fmaxf(xwf[(size_t)i * HH + lane] + bf1v, 0.0f);
        float zp = h0 * w2a  + h1 * w2b;
        float fp = h0 * wf2a + h1 * wf2b;
#pragma unroll
        for (int o = 32; o > 0; o >>= 1) {
            zp += __shfl_xor(zp, o, 64);
            fp += __shfl_xor(fp, o, 64);
        }
        if (lane == 0) {
            z[i]   = zp;
            out[i] = fp + obias;
        }
    }
}

// --------------------------- layer-2: bucket-LDS scalar aggregate -----------
__global__ __launch_bounds__(1024) void k_bagg2(
    const int* __restrict__ bstart, const int2* __restrict__ recs,
    const float* __restrict__ dinv, const float* __restrict__ z,
    float* __restrict__ out, int N)
{
    __shared__ float sacc[BNODE];
    const int bkt = blockIdx.x;
    const int tid = threadIdx.x;
    if (tid < BNODE) sacc[tid] = 0.0f;
    __syncthreads();

    const int jb = bstart[bkt], je = bstart[bkt + 1];
    for (int j = jb + tid; j < je; j += 1024) {
        int2 r = recs[j];
        atomicAdd(&sacc[r.x >> 17], z[r.x & 0x1FFFF] * __int_as_float(r.y));
    }
    __syncthreads();

    if (tid < BNODE) {
        int i = bkt * BNODE + tid;
        if (i < N) {
            float di = dinv[i];
            out[i] += sacc[tid] + z[i] * di * di;
        }
    }
}

// ---------------------------------------------------------------- launch ----
extern "C" void kernel_launch(void* const* d_in, const int* in_sizes, int n_in,
                              void* d_out, int out_size, void* d_ws, size_t ws_size,
                              hipStream_t stream)
{
    const float* x   = (const float*)d_in[0];
    const int*   ei  = (const int*)d_in[1];    // [2,E]: row=ei[e], col=ei[E+e]
    const float* W1  = (const float*)d_in[2];
    const float* b1  = (const float*)d_in[3];
    const float* Wf1 = (const float*)d_in[4];
    const float* bf1 = (const float*)d_in[5];
    const float* W2  = (const float*)d_in[6];
    const float* b2  = (const float*)d_in[7];
    const float* Wf2 = (const float*)d_in[8];
    const float* bf2 = (const float*)d_in[9];

    const int N = in_sizes[0] / FIN;   // 100000
    const int E = in_sizes[1] / 2;     // 1600000
    float* out = (float*)d_out;

    const int NB  = (N + BNODE - 1) / BNODE;   // 782 buckets
    const int NB8 = NB * 8;

    // workspace layout (all 8B-aligned):
    // xwf[N*64] f32 | xwg[N*64] bf16 | dinv[N] | z[N] | cnt[N] | cur[NB8] |
    // bstart[NB+1 pad even] | recs[E] int2
    float*          xwf    = (float*)d_ws;
    unsigned short* xwg    = (unsigned short*)(xwf + (size_t)N * HH);
    float*          dinv   = (float*)(xwg + (size_t)N * HH);
    float*          z      = dinv + N;
    int*            cnt    = (int*)(z + N);
    int*            cur    = cnt + N;
    int*            bstart = cur + NB8;
    int             bpad   = (NB + 2) & ~1;
    int2*           recs   = (int2*)(bstart + bpad);

    // zero cnt + cur in one shot (contiguous)
    hipMemsetAsync(cnt, 0, (size_t)(N + NB8) * sizeof(int), stream);

    const int egrid = (E + 255) / 256;
    k_count<<<egrid, 256, 0, stream>>>(ei + E, cnt, cur, E);
    k_scanB<<<1, 1024, 0, stream>>>(cur, bstart, NB, E);
    k_dinv<<<(N + 255) / 256, 256, 0, stream>>>(cnt, dinv, N);
    k_scatter<<<egrid, 256, 0, stream>>>(ei, dinv, cur, recs, E);

    k_gemm<<<(N + 63) / 64, 256, 0, stream>>>(x, W1, Wf1, xwg, xwf, N);

    k_bagg<<<NB, 1024, 0, stream>>>(bstart, recs, dinv, xwg, xwf,
                                    b1, bf1, W2, Wf2, b2, bf2, z, out, N);
    k_bagg2<<<NB, 1024, 0, stream>>>(bstart, recs, dinv, z, out, N);
}

// Round 7
// 438.902 us; speedup vs baseline: 2.5638x; 2.5638x over previous
//
#include <hip/hip_runtime.h>

constexpr int FIN   = 128;   // input features
constexpr int HH    = 64;    // half hidden (GCN branch width)
constexpr int BSH   = 7;     // log2(nodes per bucket)
constexpr int BNODE = 1 << BSH;   // 128 nodes / bucket
constexpr int CAP   = 4096;  // records per LDS sort chunk

// ---- bf16 helpers (manual, RNE) ----
__device__ __forceinline__ unsigned short f2bf(float f) {
    unsigned u = __float_as_uint(f);
    u += 0x7FFFu + ((u >> 16) & 1u);
    return (unsigned short)(u >> 16);
}
__device__ __forceinline__ float bflo(unsigned p) { return __uint_as_float(p << 16); }
__device__ __forceinline__ float bfhi(unsigned p) { return __uint_as_float(p & 0xFFFF0000u); }

// ------------------------------------------------------------------ GEMM ----
// [xwg | xwf] = x[N,128] @ [W1 | Wf1];  xwg = bf16 GCN half, xwf = fp32 half
__global__ __launch_bounds__(256) void k_gemm(
    const float* __restrict__ x, const float* __restrict__ W1,
    const float* __restrict__ Wf1, unsigned short* __restrict__ xwg,
    float* __restrict__ xwf, int N)
{
    __shared__ float xs[16][68];
    __shared__ float ws[16][128];

    const int tid = threadIdx.x;
    const int tx  = tid & 31;
    const int ty  = tid >> 5;
    const int nbase = blockIdx.x * 64;

    float acc[8][4];
#pragma unroll
    for (int i = 0; i < 8; ++i)
#pragma unroll
        for (int j = 0; j < 4; ++j) acc[i][j] = 0.0f;

    const int xr_row = tid >> 2;
    const int xr_kk0 = (tid & 3) * 4;
    int nload = nbase + xr_row;
    const int nclamped = (nload < N) ? nload : (N - 1);

    const int wk = tid >> 4;
    const int wc = (tid * 8) & 127;

    for (int k0 = 0; k0 < FIN; k0 += 16) {
        float4 xv = *(const float4*)(x + (size_t)nclamped * FIN + k0 + xr_kk0);
        xs[xr_kk0 + 0][xr_row] = xv.x;
        xs[xr_kk0 + 1][xr_row] = xv.y;
        xs[xr_kk0 + 2][xr_row] = xv.z;
        xs[xr_kk0 + 3][xr_row] = xv.w;
        {
            const float* src = (wc < HH) ? (W1  + (size_t)(k0 + wk) * HH + wc)
                                         : (Wf1 + (size_t)(k0 + wk) * HH + (wc - HH));
            float4 w0 = *(const float4*)(src);
            float4 w1 = *(const float4*)(src + 4);
            *(float4*)&ws[wk][wc]     = w0;
            *(float4*)&ws[wk][wc + 4] = w1;
        }
        __syncthreads();

#pragma unroll
        for (int kk = 0; kk < 16; ++kk) {
            float4 xa = *(const float4*)&xs[kk][ty * 8];
            float4 xb = *(const float4*)&xs[kk][ty * 8 + 4];
            float4 wv = *(const float4*)&ws[kk][tx * 4];
            float xr[8] = {xa.x, xa.y, xa.z, xa.w, xb.x, xb.y, xb.z, xb.w};
#pragma unroll
            for (int i = 0; i < 8; ++i) {
                acc[i][0] = fmaf(xr[i], wv.x, acc[i][0]);
                acc[i][1] = fmaf(xr[i], wv.y, acc[i][1]);
                acc[i][2] = fmaf(xr[i], wv.z, acc[i][2]);
                acc[i][3] = fmaf(xr[i], wv.w, acc[i][3]);
            }
        }
        __syncthreads();
    }

#pragma unroll
    for (int i = 0; i < 8; ++i) {
        int n = nbase + ty * 8 + i;
        if (n < N) {
            if (tx < 16) {
                ushort4 v;
                v.x = f2bf(acc[i][0]); v.y = f2bf(acc[i][1]);
                v.z = f2bf(acc[i][2]); v.w = f2bf(acc[i][3]);
                *(ushort4*)(xwg + (size_t)n * HH + tx * 4) = v;
            } else {
                float4 v = make_float4(acc[i][0], acc[i][1], acc[i][2], acc[i][3]);
                *(float4*)(xwf + (size_t)n * HH + (tx - 16) * 4) = v;
            }
        }
    }
}

// ----------------------------------------------------------- bucket build ---
__global__ void k_count(const int* __restrict__ col, int* __restrict__ cnt,
                        int* __restrict__ cur, int E)
{
    int e = blockIdx.x * blockDim.x + threadIdx.x;
    if (e >= E) return;
    int c = col[e];
    atomicAdd(cnt + c, 1);
    atomicAdd(cur + ((c >> BSH) * 8 + (blockIdx.x & 7)), 1);
}

__global__ __launch_bounds__(1024) void k_scanB(
    int* __restrict__ cur, int* __restrict__ bstart, int NB, int E)
{
    __shared__ int s[1024];
    const int t = threadIdx.x;
    const int total = NB * 8;
    const int CH = 7;
    int v[CH]; int mysum = 0;
#pragma unroll
    for (int q = 0; q < CH; ++q) {
        int idx = t * CH + q;
        v[q] = (idx < total) ? cur[idx] : 0;
        mysum += v[q];
    }
    s[t] = mysum;
    __syncthreads();
    for (int o = 1; o < 1024; o <<= 1) {
        int y = (t >= o) ? s[t - o] : 0;
        __syncthreads();
        s[t] += y;
        __syncthreads();
    }
    int running = s[t] - mysum;
#pragma unroll
    for (int q = 0; q < CH; ++q) {
        int idx = t * CH + q;
        if (idx < total) cur[idx] = running;
        running += v[q];
    }
    __syncthreads();
    for (int b = t; b < NB; b += 1024) bstart[b] = cur[b * 8];
    if (t == 0) bstart[NB] = E;
}

__global__ void k_dinv(const int* __restrict__ cnt, float* __restrict__ dinv, int N) {
    int i = blockIdx.x * blockDim.x + threadIdx.x;
    if (i < N) dinv[i] = rsqrtf((float)cnt[i] + 1.0f);
}

// recs[pos] = { row | (c_local<<17), norm }, appended per (bucket,stripe).
__global__ void k_scatter(const int* __restrict__ ei, const float* __restrict__ dinv,
                          int* __restrict__ cur, int2* __restrict__ recs, int E)
{
    int e = blockIdx.x * blockDim.x + threadIdx.x;
    if (e >= E) return;
    int r = ei[e], c = ei[E + e];
    float nrm = dinv[r] * dinv[c];
    int pos = atomicAdd(cur + ((c >> BSH) * 8 + (blockIdx.x & 7)), 1);
    recs[pos] = make_int2(r | ((c & (BNODE - 1)) << 17), __float_as_int(nrm));
}

// --------------- layer-1: in-block sort + register aggregate + epilogue -----
// one block per bucket; chunk of <=4096 records counting-sorted by local node
// in LDS; 64 groups of 16 lanes own 2 nodes each, accumulate in registers.
__global__ __launch_bounds__(1024) void k_bagg(
    const int* __restrict__ bstart, const int2* __restrict__ recs,
    const float* __restrict__ dinv,
    const unsigned short* __restrict__ xwg, const float* __restrict__ xwf,
    const float* __restrict__ b1, const float* __restrict__ bf1,
    const float* __restrict__ W2, const float* __restrict__ Wf2,
    const float* __restrict__ b2, const float* __restrict__ bf2,
    float* __restrict__ z, float* __restrict__ out, int N)
{
    __shared__ int2 sbuf[CAP];
    __shared__ int  hcnt[BNODE];
    __shared__ int  hoff[BNODE + 1];
    __shared__ int  hcur[BNODE];

    const int bkt  = blockIdx.x;
    const int tid  = threadIdx.x;
    const int g    = tid >> 4;     // group 0..63
    const int l16  = tid & 15;     // feature quad within group
    const int lane = tid & 63;
    const int wave = tid >> 6;

    const int jb = bstart[bkt], je = bstart[bkt + 1];

    float4 acc0 = make_float4(0.f, 0.f, 0.f, 0.f);
    float4 acc1 = make_float4(0.f, 0.f, 0.f, 0.f);

    for (int base = jb; base < je; base += CAP) {
        const int m = min(CAP, je - base);
        if (tid < BNODE) hcnt[tid] = 0;
        __syncthreads();
        // pass A: histogram by local node
        for (int k = tid; k < m; k += 1024)
            atomicAdd(&hcnt[recs[base + k].x >> 17], 1);
        __syncthreads();
        // scan 128 counters (wave 0)
        if (wave == 0) {
            int a = hcnt[lane];
            int b = hcnt[64 + lane];
            const int a0 = a, b0 = b;
#pragma unroll
            for (int o = 1; o < 64; o <<= 1) {
                int t = __shfl_up(a, o, 64);
                if (lane >= o) a += t;
                int u = __shfl_up(b, o, 64);
                if (lane >= o) b += u;
            }
            int atot = __shfl(a, 63, 64);
            b += atot;
            hoff[lane + 1]      = a;       // inclusive => exclusive of next
            hoff[64 + lane + 1] = b;
            if (lane == 0) hoff[0] = 0;
            hcur[lane]      = a - a0;      // exclusive offsets as cursors
            hcur[64 + lane] = b - b0;
        }
        __syncthreads();
        // pass B: scatter records into sorted LDS buffer
        for (int k = tid; k < m; k += 1024) {
            int2 r = recs[base + k];
            int pos = atomicAdd(&hcur[r.x >> 17], 1);
            sbuf[pos] = r;
        }
        __syncthreads();
        // pass C: group g accumulates nodes 2g, 2g+1 in registers
#pragma unroll
        for (int nn = 0; nn < 2; ++nn) {
            const int n = g * 2 + nn;
            const int s = hoff[n], e = hoff[n + 1];
            float4 A = nn ? acc1 : acc0;
            for (int j0 = s; j0 < e; j0 += 16) {
                const int lim = min(16, e - j0);
                int2 rr = (l16 < lim) ? sbuf[j0 + l16] : make_int2(0, 0);
#pragma unroll 4
                for (int t = 0; t < lim; ++t) {
                    int   pk = __shfl(rr.x, t, 16);
                    float nr = __shfl(__int_as_float(rr.y), t, 16);
                    uint2 p = *(const uint2*)(xwg + (size_t)(pk & 0x1FFFF) * HH + l16 * 4);
                    A.x = fmaf(bflo(p.x), nr, A.x);
                    A.y = fmaf(bfhi(p.x), nr, A.y);
                    A.z = fmaf(bflo(p.y), nr, A.z);
                    A.w = fmaf(bfhi(p.y), nr, A.w);
                }
            }
            if (nn) acc1 = A; else acc0 = A;
        }
        __syncthreads();   // protect LDS reuse in next chunk
    }

    // ---- epilogue: per-group, 2 nodes ----
    const float4 b1v  = *(const float4*)(b1  + l16 * 4);
    const float4 bf1v = *(const float4*)(bf1 + l16 * 4);
    const float4 w2a  = *(const float4*)(W2  + l16 * 4);
    const float4 w2b  = *(const float4*)(W2  + HH + l16 * 4);
    const float4 wf2a = *(const float4*)(Wf2 + l16 * 4);
    const float4 wf2b = *(const float4*)(Wf2 + HH + l16 * 4);
    const float obias = b2[0] + bf2[0];

#pragma unroll
    for (int nn = 0; nn < 2; ++nn) {
        const int n = g * 2 + nn;
        const int i = bkt * BNODE + n;
        if (i >= N) continue;
        float4 A = nn ? acc1 : acc0;
        const float di = dinv[i];
        const float dd = di * di;
        uint2 p = *(const uint2*)(xwg + (size_t)i * HH + l16 * 4);
        A.x = fmaf(bflo(p.x), dd, A.x);
        A.y = fmaf(bfhi(p.x), dd, A.y);
        A.z = fmaf(bflo(p.y), dd, A.z);
        A.w = fmaf(bfhi(p.y), dd, A.w);

        float4 x1 = *(const float4*)(xwf + (size_t)i * HH + l16 * 4);
        float4 h0, h1;
        h0.x = fmaxf(A.x + b1v.x, 0.f);   h0.y = fmaxf(A.y + b1v.y, 0.f);
        h0.z = fmaxf(A.z + b1v.z, 0.f);   h0.w = fmaxf(A.w + b1v.w, 0.f);
        h1.x = fmaxf(x1.x + bf1v.x, 0.f); h1.y = fmaxf(x1.y + bf1v.y, 0.f);
        h1.z = fmaxf(x1.z + bf1v.z, 0.f); h1.w = fmaxf(x1.w + bf1v.w, 0.f);

        float zp = h0.x * w2a.x + h0.y * w2a.y + h0.z * w2a.z + h0.w * w2a.w
                 + h1.x * w2b.x + h1.y * w2b.y + h1.z * w2b.z + h1.w * w2b.w;
        float fp = h0.x * wf2a.x + h0.y * wf2a.y + h0.z * wf2a.z + h0.w * wf2a.w
                 + h1.x * wf2b.x + h1.y * wf2b.y + h1.z * wf2b.z + h1.w * wf2b.w;
#pragma unroll
        for (int o = 8; o > 0; o >>= 1) {
            zp += __shfl_xor(zp, o, 16);
            fp += __shfl_xor(fp, o, 16);
        }
        if (l16 == 0) {
            z[i]   = zp;
            out[i] = fp + obias;
        }
    }
}

// --------------------------- layer-2: bucket-LDS scalar aggregate -----------
__global__ __launch_bounds__(1024) void k_bagg2(
    const int* __restrict__ bstart, const int2* __restrict__ recs,
    const float* __restrict__ dinv, const float* __restrict__ z,
    float* __restrict__ out, int N)
{
    __shared__ float sacc[BNODE];
    const int bkt = blockIdx.x;
    const int tid = threadIdx.x;
    if (tid < BNODE) sacc[tid] = 0.0f;
    __syncthreads();

    const int jb = bstart[bkt], je = bstart[bkt + 1];
    for (int j = jb + tid; j < je; j += 1024) {
        int2 r = recs[j];
        atomicAdd(&sacc[r.x >> 17], z[r.x & 0x1FFFF] * __int_as_float(r.y));
    }
    __syncthreads();

    if (tid < BNODE) {
        int i = bkt * BNODE + tid;
        if (i < N) {
            float di = dinv[i];
            out[i] += sacc[tid] + z[i] * di * di;
        }
    }
}

// ---------------------------------------------------------------- launch ----
extern "C" void kernel_launch(void* const* d_in, const int* in_sizes, int n_in,
                              void* d_out, int out_size, void* d_ws, size_t ws_size,
                              hipStream_t stream)
{
    const float* x   = (const float*)d_in[0];
    const int*   ei  = (const int*)d_in[1];    // [2,E]: row=ei[e], col=ei[E+e]
    const float* W1  = (const float*)d_in[2];
    const float* b1  = (const float*)d_in[3];
    const float* Wf1 = (const float*)d_in[4];
    const float* bf1 = (const float*)d_in[5];
    const float* W2  = (const float*)d_in[6];
    const float* b2  = (const float*)d_in[7];
    const float* Wf2 = (const float*)d_in[8];
    const float* bf2 = (const float*)d_in[9];

    const int N = in_sizes[0] / FIN;   // 100000
    const int E = in_sizes[1] / 2;     // 1600000
    float* out = (float*)d_out;

    const int NB  = (N + BNODE - 1) / BNODE;   // 782 buckets
    const int NB8 = NB * 8;

    // workspace layout (all 8B-aligned):
    // xwf[N*64] f32 | xwg[N*64] bf16 | dinv[N] | z[N] | cnt[N] | cur[NB8] |
    // bstart[NB+1 pad even] | recs[E] int2
    float*          xwf    = (float*)d_ws;
    unsigned short* xwg    = (unsigned short*)(xwf + (size_t)N * HH);
    float*          dinv   = (float*)(xwg + (size_t)N * HH);
    float*          z      = dinv + N;
    int*            cnt    = (int*)(z + N);
    int*            cur    = cnt + N;
    int*            bstart = cur + NB8;
    int             bpad   = (NB + 2) & ~1;
    int2*           recs   = (int2*)(bstart + bpad);

    hipMemsetAsync(cnt, 0, (size_t)(N + NB8) * sizeof(int), stream);

    const int egrid = (E + 255) / 256;
    k_count<<<egrid, 256, 0, stream>>>(ei + E, cnt, cur, E);
    k_scanB<<<1, 1024, 0, stream>>>(cur, bstart, NB, E);
    k_dinv<<<(N + 255) / 256, 256, 0, stream>>>(cnt, dinv, N);
    k_scatter<<<egrid, 256, 0, stream>>>(ei, dinv, cur, recs, E);

    k_gemm<<<(N + 63) / 64, 256, 0, stream>>>(x, W1, Wf1, xwg, xwf, N);

    k_bagg<<<NB, 1024, 0, stream>>>(bstart, recs, dinv, xwg, xwf,
                                    b1, bf1, W2, Wf2, b2, bf2, z, out, N);
    k_bagg2<<<NB, 1024, 0, stream>>>(bstart, recs, dinv, z, out, N);
}

// Round 8
// 377.750 us; speedup vs baseline: 2.9788x; 1.1619x over previous
//
#include <hip/hip_runtime.h>

constexpr int FIN   = 128;   // input features
constexpr int HH    = 64;    // half hidden (GCN branch width)
constexpr int BSH   = 7;     // log2(nodes per bucket)
constexpr int BNODE = 1 << BSH;   // 128 nodes / bucket
constexpr int CAP   = 4096;  // records per LDS sort chunk

// ---- bf16 helpers (manual, RNE) ----
__device__ __forceinline__ unsigned short f2bf(float f) {
    unsigned u = __float_as_uint(f);
    u += 0x7FFFu + ((u >> 16) & 1u);
    return (unsigned short)(u >> 16);
}
__device__ __forceinline__ float bflo(unsigned p) { return __uint_as_float(p << 16); }
__device__ __forceinline__ float bfhi(unsigned p) { return __uint_as_float(p & 0xFFFF0000u); }

// ------------------------------------------------------------------ GEMM ----
// xwg = bf16( dinv[n] * (x @ W1) )   (pre-scaled GCN half)
// xwf = f32 ( x @ Wf1 )              (linear half)
__global__ __launch_bounds__(256) void k_gemm(
    const float* __restrict__ x, const float* __restrict__ W1,
    const float* __restrict__ Wf1, const float* __restrict__ dinv,
    unsigned short* __restrict__ xwg, float* __restrict__ xwf, int N)
{
    __shared__ float xs[16][68];
    __shared__ float ws[16][128];

    const int tid = threadIdx.x;
    const int tx  = tid & 31;
    const int ty  = tid >> 5;
    const int nbase = blockIdx.x * 64;

    float acc[8][4];
#pragma unroll
    for (int i = 0; i < 8; ++i)
#pragma unroll
        for (int j = 0; j < 4; ++j) acc[i][j] = 0.0f;

    const int xr_row = tid >> 2;
    const int xr_kk0 = (tid & 3) * 4;
    int nload = nbase + xr_row;
    const int nclamped = (nload < N) ? nload : (N - 1);

    const int wk = tid >> 4;
    const int wc = (tid * 8) & 127;

    for (int k0 = 0; k0 < FIN; k0 += 16) {
        float4 xv = *(const float4*)(x + (size_t)nclamped * FIN + k0 + xr_kk0);
        xs[xr_kk0 + 0][xr_row] = xv.x;
        xs[xr_kk0 + 1][xr_row] = xv.y;
        xs[xr_kk0 + 2][xr_row] = xv.z;
        xs[xr_kk0 + 3][xr_row] = xv.w;
        {
            const float* src = (wc < HH) ? (W1  + (size_t)(k0 + wk) * HH + wc)
                                         : (Wf1 + (size_t)(k0 + wk) * HH + (wc - HH));
            float4 w0 = *(const float4*)(src);
            float4 w1 = *(const float4*)(src + 4);
            *(float4*)&ws[wk][wc]     = w0;
            *(float4*)&ws[wk][wc + 4] = w1;
        }
        __syncthreads();

#pragma unroll
        for (int kk = 0; kk < 16; ++kk) {
            float4 xa = *(const float4*)&xs[kk][ty * 8];
            float4 xb = *(const float4*)&xs[kk][ty * 8 + 4];
            float4 wv = *(const float4*)&ws[kk][tx * 4];
            float xr[8] = {xa.x, xa.y, xa.z, xa.w, xb.x, xb.y, xb.z, xb.w};
#pragma unroll
            for (int i = 0; i < 8; ++i) {
                acc[i][0] = fmaf(xr[i], wv.x, acc[i][0]);
                acc[i][1] = fmaf(xr[i], wv.y, acc[i][1]);
                acc[i][2] = fmaf(xr[i], wv.z, acc[i][2]);
                acc[i][3] = fmaf(xr[i], wv.w, acc[i][3]);
            }
        }
        __syncthreads();
    }

#pragma unroll
    for (int i = 0; i < 8; ++i) {
        int n = nbase + ty * 8 + i;
        if (n < N) {
            if (tx < 16) {   // GCN half, pre-scaled by dinv[n] -> bf16
                float di = dinv[n];
                ushort4 v;
                v.x = f2bf(acc[i][0] * di); v.y = f2bf(acc[i][1] * di);
                v.z = f2bf(acc[i][2] * di); v.w = f2bf(acc[i][3] * di);
                *(ushort4*)(xwg + (size_t)n * HH + tx * 4) = v;
            } else {
                float4 v = make_float4(acc[i][0], acc[i][1], acc[i][2], acc[i][3]);
                *(float4*)(xwf + (size_t)n * HH + (tx - 16) * 4) = v;
            }
        }
    }
}

// ----------------------------------------------------------- bucket build ---
// count per-(bucket,stripe) record counts only (no per-node atomics).
__global__ void k_count(const int* __restrict__ col, int* __restrict__ cur, int E)
{
    int e = blockIdx.x * blockDim.x + threadIdx.x;
    if (e >= E) return;
    atomicAdd(cur + ((col[e] >> BSH) * 8 + (blockIdx.x & 7)), 1);
}

__global__ __launch_bounds__(1024) void k_scanB(
    int* __restrict__ cur, int* __restrict__ bstart, int NB, int E)
{
    __shared__ int s[1024];
    const int t = threadIdx.x;
    const int total = NB * 8;
    const int CH = 7;
    int v[CH]; int mysum = 0;
#pragma unroll
    for (int q = 0; q < CH; ++q) {
        int idx = t * CH + q;
        v[q] = (idx < total) ? cur[idx] : 0;
        mysum += v[q];
    }
    s[t] = mysum;
    __syncthreads();
    for (int o = 1; o < 1024; o <<= 1) {
        int y = (t >= o) ? s[t - o] : 0;
        __syncthreads();
        s[t] += y;
        __syncthreads();
    }
    int running = s[t] - mysum;
#pragma unroll
    for (int q = 0; q < CH; ++q) {
        int idx = t * CH + q;
        if (idx < total) cur[idx] = running;
        running += v[q];
    }
    __syncthreads();
    for (int b = t; b < NB; b += 1024) bstart[b] = cur[b * 8];
    if (t == 0) bstart[NB] = E;
}

// recs[pos] = row | (c_local<<17), appended per (bucket,stripe) cursor.
// Sequential positions per cursor -> full-line write combining.
__global__ void k_scatter(const int* __restrict__ ei, int* __restrict__ cur,
                          unsigned* __restrict__ recs, int E)
{
    int e = blockIdx.x * blockDim.x + threadIdx.x;
    if (e >= E) return;
    int r = ei[e], c = ei[E + e];
    int pos = atomicAdd(cur + ((c >> BSH) * 8 + (blockIdx.x & 7)), 1);
    recs[pos] = (unsigned)r | ((unsigned)(c & (BNODE - 1)) << 17);
}

// per-bucket degree histogram -> dinv
__global__ __launch_bounds__(1024) void k_hist(
    const int* __restrict__ bstart, const unsigned* __restrict__ recs,
    float* __restrict__ dinv, int N)
{
    __shared__ int h[BNODE];
    const int bkt = blockIdx.x;
    const int tid = threadIdx.x;
    if (tid < BNODE) h[tid] = 0;
    __syncthreads();
    const int jb = bstart[bkt], je = bstart[bkt + 1];
    for (int j = jb + tid; j < je; j += 1024)
        atomicAdd(&h[recs[j] >> 17], 1);
    __syncthreads();
    if (tid < BNODE) {
        int i = bkt * BNODE + tid;
        if (i < N) dinv[i] = rsqrtf((float)h[tid] + 1.0f);
    }
}

// --------------- layer-1: in-block sort + register aggregate + epilogue -----
// one block per bucket; records counting-sorted by local node in LDS;
// 64 groups of 16 lanes own 2 nodes each, accumulate in registers (pure adds:
// xwg rows are pre-scaled by dinv[row]).
__global__ __launch_bounds__(1024) void k_bagg(
    const int* __restrict__ bstart, const unsigned* __restrict__ recs,
    const float* __restrict__ dinv,
    const unsigned short* __restrict__ xwg, const float* __restrict__ xwf,
    const float* __restrict__ b1, const float* __restrict__ bf1,
    const float* __restrict__ W2, const float* __restrict__ Wf2,
    const float* __restrict__ b2, const float* __restrict__ bf2,
    float* __restrict__ zs, float* __restrict__ out, int N)
{
    __shared__ unsigned sbuf[CAP];
    __shared__ int hcnt[BNODE];
    __shared__ int hoff[BNODE + 1];
    __shared__ int hcur[BNODE];

    const int bkt  = blockIdx.x;
    const int tid  = threadIdx.x;
    const int g    = tid >> 4;     // group 0..63
    const int l16  = tid & 15;     // feature quad within group
    const int lane = tid & 63;
    const int wave = tid >> 6;

    const int jb = bstart[bkt], je = bstart[bkt + 1];

    float4 acc0 = make_float4(0.f, 0.f, 0.f, 0.f);
    float4 acc1 = make_float4(0.f, 0.f, 0.f, 0.f);

    for (int base = jb; base < je; base += CAP) {
        const int m = min(CAP, je - base);
        if (tid < BNODE) hcnt[tid] = 0;
        __syncthreads();
        for (int k = tid; k < m; k += 1024)
            atomicAdd(&hcnt[recs[base + k] >> 17], 1);
        __syncthreads();
        if (wave == 0) {
            int a = hcnt[lane];
            int b = hcnt[64 + lane];
            const int a0 = a, b0 = b;
#pragma unroll
            for (int o = 1; o < 64; o <<= 1) {
                int t = __shfl_up(a, o, 64);
                if (lane >= o) a += t;
                int u = __shfl_up(b, o, 64);
                if (lane >= o) b += u;
            }
            int atot = __shfl(a, 63, 64);
            b += atot;
            hoff[lane + 1]      = a;
            hoff[64 + lane + 1] = b;
            if (lane == 0) hoff[0] = 0;
            hcur[lane]      = a - a0;
            hcur[64 + lane] = b - b0;
        }
        __syncthreads();
        for (int k = tid; k < m; k += 1024) {
            unsigned r = recs[base + k];
            int pos = atomicAdd(&hcur[r >> 17], 1);
            sbuf[pos] = r;
        }
        __syncthreads();
#pragma unroll
        for (int nn = 0; nn < 2; ++nn) {
            const int n = g * 2 + nn;
            const int s = hoff[n], e = hoff[n + 1];
            float4 A = nn ? acc1 : acc0;
            for (int j0 = s; j0 < e; j0 += 16) {
                const int lim = min(16, e - j0);
                unsigned rr = (l16 < lim) ? sbuf[j0 + l16] : 0u;
#pragma unroll 4
                for (int t = 0; t < lim; ++t) {
                    int row = __shfl((int)rr, t, 16) & 0x1FFFF;
                    uint2 p = *(const uint2*)(xwg + (size_t)row * HH + l16 * 4);
                    A.x += bflo(p.x);
                    A.y += bfhi(p.x);
                    A.z += bflo(p.y);
                    A.w += bfhi(p.y);
                }
            }
            if (nn) acc1 = A; else acc0 = A;
        }
        __syncthreads();
    }

    // ---- epilogue: per-group, 2 nodes ----
    const float4 b1v  = *(const float4*)(b1  + l16 * 4);
    const float4 bf1v = *(const float4*)(bf1 + l16 * 4);
    const float4 w2a  = *(const float4*)(W2  + l16 * 4);
    const float4 w2b  = *(const float4*)(W2  + HH + l16 * 4);
    const float4 wf2a = *(const float4*)(Wf2 + l16 * 4);
    const float4 wf2b = *(const float4*)(Wf2 + HH + l16 * 4);
    const float obias = b2[0] + bf2[0];

#pragma unroll
    for (int nn = 0; nn < 2; ++nn) {
        const int n = g * 2 + nn;
        const int i = bkt * BNODE + n;
        if (i >= N) continue;
        float4 A = nn ? acc1 : acc0;
        const float di = dinv[i];
        // self loop: xwg[i] is already dinv[i]*xw1[i]
        uint2 p = *(const uint2*)(xwg + (size_t)i * HH + l16 * 4);
        A.x += bflo(p.x);
        A.y += bfhi(p.x);
        A.z += bflo(p.y);
        A.w += bfhi(p.y);

        float4 x1 = *(const float4*)(xwf + (size_t)i * HH + l16 * 4);
        float4 h0, h1;
        h0.x = fmaxf(fmaf(A.x, di, b1v.x), 0.f);
        h0.y = fmaxf(fmaf(A.y, di, b1v.y), 0.f);
        h0.z = fmaxf(fmaf(A.z, di, b1v.z), 0.f);
        h0.w = fmaxf(fmaf(A.w, di, b1v.w), 0.f);
        h1.x = fmaxf(x1.x + bf1v.x, 0.f); h1.y = fmaxf(x1.y + bf1v.y, 0.f);
        h1.z = fmaxf(x1.z + bf1v.z, 0.f); h1.w = fmaxf(x1.w + bf1v.w, 0.f);

        float zp = h0.x * w2a.x + h0.y * w2a.y + h0.z * w2a.z + h0.w * w2a.w
                 + h1.x * w2b.x + h1.y * w2b.y + h1.z * w2b.z + h1.w * w2b.w;
        float fp = h0.x * wf2a.x + h0.y * wf2a.y + h0.z * wf2a.z + h0.w * wf2a.w
                 + h1.x * wf2b.x + h1.y * wf2b.y + h1.z * wf2b.z + h1.w * wf2b.w;
#pragma unroll
        for (int o = 8; o > 0; o >>= 1) {
            zp += __shfl_xor(zp, o, 16);
            fp += __shfl_xor(fp, o, 16);
        }
        if (l16 == 0) {
            zs[i]  = zp * di;          // pre-scaled for layer-2 factorization
            out[i] = fp + obias;
        }
    }
}

// --------------------------- layer-2: bucket-LDS scalar aggregate -----------
// zs[r] = z[r]*dinv[r]; out[c] += dinv[c] * (sum_edges zs[r] + zs[c])
__global__ __launch_bounds__(1024) void k_bagg2(
    const int* __restrict__ bstart, const unsigned* __restrict__ recs,
    const float* __restrict__ dinv, const float* __restrict__ zs,
    float* __restrict__ out, int N)
{
    __shared__ float sacc[BNODE];
    const int bkt = blockIdx.x;
    const int tid = threadIdx.x;
    if (tid < BNODE) sacc[tid] = 0.0f;
    __syncthreads();

    const int jb = bstart[bkt], je = bstart[bkt + 1];
    for (int j = jb + tid; j < je; j += 1024) {
        unsigned r = recs[j];
        atomicAdd(&sacc[r >> 17], zs[r & 0x1FFFF]);
    }
    __syncthreads();

    if (tid < BNODE) {
        int i = bkt * BNODE + tid;
        if (i < N)
            out[i] += dinv[i] * (sacc[tid] + zs[i]);
    }
}

// ---------------------------------------------------------------- launch ----
extern "C" void kernel_launch(void* const* d_in, const int* in_sizes, int n_in,
                              void* d_out, int out_size, void* d_ws, size_t ws_size,
                              hipStream_t stream)
{
    const float* x   = (const float*)d_in[0];
    const int*   ei  = (const int*)d_in[1];    // [2,E]: row=ei[e], col=ei[E+e]
    const float* W1  = (const float*)d_in[2];
    const float* b1  = (const float*)d_in[3];
    const float* Wf1 = (const float*)d_in[4];
    const float* bf1 = (const float*)d_in[5];
    const float* W2  = (const float*)d_in[6];
    const float* b2  = (const float*)d_in[7];
    const float* Wf2 = (const float*)d_in[8];
    const float* bf2 = (const float*)d_in[9];

    const int N = in_sizes[0] / FIN;   // 100000
    const int E = in_sizes[1] / 2;     // 1600000
    float* out = (float*)d_out;

    const int NB  = (N + BNODE - 1) / BNODE;   // 782 buckets
    const int NB8 = NB * 8;

    // workspace layout (all 8B-aligned):
    // xwf[N*64] f32 | xwg[N*64] bf16 | dinv[N] | zs[N] | cur[NB8] |
    // bstart[NB+1 pad] | recs[E] uint
    float*          xwf    = (float*)d_ws;
    unsigned short* xwg    = (unsigned short*)(xwf + (size_t)N * HH);
    float*          dinv   = (float*)(xwg + (size_t)N * HH);
    float*          zs     = dinv + N;
    int*            cur    = (int*)(zs + N);
    int*            bstart = cur + NB8;
    int             bpad   = (NB + 2) & ~1;
    unsigned*       recs   = (unsigned*)(bstart + bpad);

    hipMemsetAsync(cur, 0, (size_t)NB8 * sizeof(int), stream);

    const int egrid = (E + 255) / 256;
    k_count<<<egrid, 256, 0, stream>>>(ei + E, cur, E);
    k_scanB<<<1, 1024, 0, stream>>>(cur, bstart, NB, E);
    k_scatter<<<egrid, 256, 0, stream>>>(ei, cur, recs, E);
    k_hist<<<NB, 1024, 0, stream>>>(bstart, recs, dinv, N);

    k_gemm<<<(N + 63) / 64, 256, 0, stream>>>(x, W1, Wf1, dinv, xwg, xwf, N);

    k_bagg<<<NB, 1024, 0, stream>>>(bstart, recs, dinv, xwg, xwf,
                                    b1, bf1, W2, Wf2, b2, bf2, zs, out, N);
    k_bagg2<<<NB, 1024, 0, stream>>>(bstart, recs, dinv, zs, out, N);
}